// Round 1
// baseline (241.093 us; speedup 1.0000x reference)
//
#include <hip/hip_runtime.h>

#define T_TOK 512
#define HDIM 2048
#define NEXP 8
#define IDIM 4096

#define G1_BM 128
#define G1_BN 64
#define G2_BN 32
#define BK 64

typedef float f32x4 __attribute__((ext_vector_type(4)));
typedef __bf16 bf16x8 __attribute__((ext_vector_type(8)));
typedef unsigned short ushort8 __attribute__((ext_vector_type(8)));

// fp32 -> bf16 round-to-nearest-even (values are finite; no NaN handling needed)
static __device__ __forceinline__ unsigned short f2bf(float f) {
    unsigned int u = __float_as_uint(f);
    u = (u + 0x7fffu + ((u >> 16) & 1u)) >> 16;
    return (unsigned short)u;
}

// async global->LDS, 16 bytes per lane; LDS dest = wave-uniform base + lane*16
static __device__ __forceinline__ void gload_lds16(const void* g, void* l) {
    auto gp = reinterpret_cast<const unsigned int __attribute__((address_space(1)))*>(
        reinterpret_cast<unsigned long long>(g));
    auto lp = reinterpret_cast<unsigned int __attribute__((address_space(3)))*>(
        static_cast<unsigned int>(reinterpret_cast<unsigned long long>(l)));
    __builtin_amdgcn_global_load_lds(gp, lp, 16, 0, 0);
}

// ---------------- routing: top-1 expert, sigmoid scale, sort tokens by expert ----
__global__ void k_route(const float* __restrict__ logits,
                        int* __restrict__ off, int* __restrict__ tok,
                        float* __restrict__ scale) {
    __shared__ int cnt[NEXP], cur[NEXP];
    const int t = threadIdx.x;  // one thread per token, 512 threads
    if (t < NEXP) cnt[t] = 0;
    __syncthreads();
    float m = logits[t * NEXP];
    int a = 0;
#pragma unroll
    for (int j = 1; j < NEXP; ++j) {
        float v = logits[t * NEXP + j];
        if (v > m) { m = v; a = j; }
    }
    scale[t] = 1.f / (1.f + __expf(-m));
    atomicAdd(&cnt[a], 1);
    __syncthreads();
    if (t == 0) {
        int o = 0;
        for (int e = 0; e < NEXP; ++e) { off[e] = o; cur[e] = o; o += cnt[e]; }
        off[NEXP] = o;
    }
    __syncthreads();
    int r = atomicAdd(&cur[a], 1);
    tok[r] = t;
}

// ---------------- gather + scale + bf16 cast: xs_sorted[pos] = bf16(x[tok[pos]]*s)
__global__ void k_gather(const float* __restrict__ x, const int* __restrict__ tok,
                         const float* __restrict__ scale,
                         unsigned short* __restrict__ xs) {
    const int pos = blockIdx.x;
    const int t = tok[pos];
    const float s = scale[t];
    const int c = threadIdx.x * 8;  // 256 threads * 8 = 2048
    const float4* src = (const float4*)(x + (size_t)t * HDIM + c);
    float4 v0 = src[0], v1 = src[1];
    ushort8 o;
    o[0] = f2bf(v0.x * s); o[1] = f2bf(v0.y * s);
    o[2] = f2bf(v0.z * s); o[3] = f2bf(v0.w * s);
    o[4] = f2bf(v1.x * s); o[5] = f2bf(v1.y * s);
    o[6] = f2bf(v1.z * s); o[7] = f2bf(v1.w * s);
    *(ushort8*)(xs + (size_t)pos * HDIM + c) = o;
}

// ---------------- GEMM1: gate/up projections + SiLU, grouped by expert ----------
// grid: 8 experts * 64 n-tiles. Block: 256 thr (2x2 waves), C-tile 128x64 (x2 mats)
__global__ void k_moe1(const unsigned short* __restrict__ xs,
                       const float* __restrict__ w1,
                       const float* __restrict__ w3,
                       const int* __restrict__ off,
                       unsigned short* __restrict__ hbuf) {
    __shared__ unsigned short sA[G1_BM * BK];  // 16 KiB bf16
    __shared__ float sB1[G1_BN * BK];          // 16 KiB fp32
    __shared__ float sB3[G1_BN * BK];          // 16 KiB fp32

    const int tid = threadIdx.x;
    const int w = tid >> 6, l = tid & 63;
    const int wr = w >> 1, wc = w & 1;
    const int e = blockIdx.x >> 6;
    const int n0 = (blockIdx.x & 63) * G1_BN;
    const int pos_beg = off[e], pos_end = off[e + 1];

    const float* bw1 = w1 + (size_t)e * IDIM * HDIM + (size_t)n0 * HDIM;
    const float* bw3 = w3 + (size_t)e * IDIM * HDIM + (size_t)n0 * HDIM;

    for (int m0 = pos_beg; m0 < pos_end; m0 += G1_BM) {
        f32x4 zero = {0.f, 0.f, 0.f, 0.f};
        f32x4 accG[4][2], accU[4][2];
#pragma unroll
        for (int i = 0; i < 4; ++i)
#pragma unroll
            for (int j = 0; j < 2; ++j) { accG[i][j] = zero; accU[i][j] = zero; }

#pragma unroll 1
        for (int ks = 0; ks < HDIM / BK; ++ks) {
            const int k0 = ks * BK;
            // stage A tile [128][64] bf16 (rows are sorted positions; clamp pads)
#pragma unroll
            for (int j = 0; j < 4; ++j) {
                const int o = j * 4096 + w * 1024;  // byte offset in sA
                const int row = (o >> 7) + (l >> 3);
                int gr = m0 + row; gr = gr < T_TOK ? gr : T_TOK - 1;
                gload_lds16(xs + (size_t)gr * HDIM + (k0 + ((l & 7) << 3)),
                            (char*)sA + o);
            }
            // stage B tiles [64][64] fp32 for w1 and w3
#pragma unroll
            for (int j = 0; j < 4; ++j) {
                const int o = j * 4096 + w * 1024;
                const int row = (o >> 8) + (l >> 4);
                const int c = (l & 15) << 2;
                gload_lds16(bw1 + (size_t)row * HDIM + (k0 + c), (char*)sB1 + o);
                gload_lds16(bw3 + (size_t)row * HDIM + (k0 + c), (char*)sB3 + o);
            }
            asm volatile("s_waitcnt vmcnt(0)" ::: "memory");
            __syncthreads();

#pragma unroll
            for (int kk = 0; kk < 2; ++kk) {
                const int kf = kk * 32 + ((l >> 4) << 3);
                bf16x8 a[4];
#pragma unroll
                for (int fm = 0; fm < 4; ++fm)
                    a[fm] = *(const bf16x8*)&sA[(wr * 64 + fm * 16 + (l & 15)) * BK + kf];
#pragma unroll
                for (int fn = 0; fn < 2; ++fn) {
                    const int br = (wc * 32 + fn * 16 + (l & 15)) * BK + kf;
                    f32x4 g0 = *(const f32x4*)&sB1[br];
                    f32x4 g1 = *(const f32x4*)&sB1[br + 4];
                    f32x4 u0 = *(const f32x4*)&sB3[br];
                    f32x4 u1 = *(const f32x4*)&sB3[br + 4];
                    bf16x8 bg, bu;
#pragma unroll
                    for (int q = 0; q < 4; ++q) {
                        bg[q] = (__bf16)g0[q]; bg[q + 4] = (__bf16)g1[q];
                        bu[q] = (__bf16)u0[q]; bu[q + 4] = (__bf16)u1[q];
                    }
#pragma unroll
                    for (int fm = 0; fm < 4; ++fm) {
                        accG[fm][fn] = __builtin_amdgcn_mfma_f32_16x16x32_bf16(
                            a[fm], bg, accG[fm][fn], 0, 0, 0);
                        accU[fm][fn] = __builtin_amdgcn_mfma_f32_16x16x32_bf16(
                            a[fm], bu, accU[fm][fn], 0, 0, 0);
                    }
                }
            }
            __syncthreads();
        }

        // epilogue: h = silu(gate) * up -> bf16
#pragma unroll
        for (int fm = 0; fm < 4; ++fm)
#pragma unroll
            for (int fn = 0; fn < 2; ++fn)
#pragma unroll
                for (int r = 0; r < 4; ++r) {
                    const int rowl = wr * 64 + fm * 16 + ((l >> 4) << 2) + r;
                    const int pos = m0 + rowl;
                    if (pos < pos_end) {
                        const float gv = accG[fm][fn][r];
                        const float uv = accU[fm][fn][r];
                        const float hv = gv / (1.f + __expf(-gv)) * uv;
                        hbuf[(size_t)pos * IDIM + n0 + wc * 32 + fn * 16 + (l & 15)] =
                            f2bf(hv);
                    }
                }
    }
}

// ---------------- GEMM2: down projection + scatter to out ----------------------
// grid: 8 experts * 64 h-tiles of 32. Block 256 thr, C-tile 128x32, K=4096
__global__ void k_moe2(const unsigned short* __restrict__ hbuf,
                       const float* __restrict__ w2,
                       const int* __restrict__ off,
                       const int* __restrict__ tok,
                       float* __restrict__ out) {
    __shared__ unsigned short sA[G1_BM * BK];  // 16 KiB bf16
    __shared__ float sB[G2_BN * BK];           // 8 KiB fp32

    const int tid = threadIdx.x;
    const int w = tid >> 6, l = tid & 63;
    const int wr = w >> 1, wc = w & 1;
    const int e = blockIdx.x >> 6;
    const int n0 = (blockIdx.x & 63) * G2_BN;
    const int pos_beg = off[e], pos_end = off[e + 1];
    const float* bw2 = w2 + (size_t)e * HDIM * IDIM + (size_t)n0 * IDIM;

    for (int m0 = pos_beg; m0 < pos_end; m0 += G1_BM) {
        f32x4 zero = {0.f, 0.f, 0.f, 0.f};
        f32x4 acc[4];
#pragma unroll
        for (int i = 0; i < 4; ++i) acc[i] = zero;

#pragma unroll 1
        for (int ks = 0; ks < IDIM / BK; ++ks) {
            const int k0 = ks * BK;
#pragma unroll
            for (int j = 0; j < 4; ++j) {
                const int o = j * 4096 + w * 1024;
                const int row = (o >> 7) + (l >> 3);
                int gr = m0 + row; gr = gr < T_TOK ? gr : T_TOK - 1;
                gload_lds16(hbuf + (size_t)gr * IDIM + (k0 + ((l & 7) << 3)),
                            (char*)sA + o);
            }
#pragma unroll
            for (int j = 0; j < 2; ++j) {
                const int o = j * 4096 + w * 1024;
                const int row = (o >> 8) + (l >> 4);
                const int c = (l & 15) << 2;
                gload_lds16(bw2 + (size_t)row * IDIM + (k0 + c), (char*)sB + o);
            }
            asm volatile("s_waitcnt vmcnt(0)" ::: "memory");
            __syncthreads();

#pragma unroll
            for (int kk = 0; kk < 2; ++kk) {
                const int kf = kk * 32 + ((l >> 4) << 3);
                const int br = (wc * 16 + (l & 15)) * BK + kf;
                f32x4 b0 = *(const f32x4*)&sB[br];
                f32x4 b1 = *(const f32x4*)&sB[br + 4];
                bf16x8 bb;
#pragma unroll
                for (int q = 0; q < 4; ++q) {
                    bb[q] = (__bf16)b0[q]; bb[q + 4] = (__bf16)b1[q];
                }
#pragma unroll
                for (int fm = 0; fm < 4; ++fm) {
                    bf16x8 a = *(const bf16x8*)&sA[(wr * 64 + fm * 16 + (l & 15)) * BK + kf];
                    acc[fm] = __builtin_amdgcn_mfma_f32_16x16x32_bf16(a, bb, acc[fm], 0, 0, 0);
                }
            }
            __syncthreads();
        }

#pragma unroll
        for (int fm = 0; fm < 4; ++fm)
#pragma unroll
            for (int r = 0; r < 4; ++r) {
                const int rowl = wr * 64 + fm * 16 + ((l >> 4) << 2) + r;
                const int pos = m0 + rowl;
                if (pos < pos_end) {
                    const int t = tok[pos];
                    out[(size_t)t * HDIM + n0 + wc * 16 + (l & 15)] = acc[fm][r];
                }
            }
    }
}

extern "C" void kernel_launch(void* const* d_in, const int* in_sizes, int n_in,
                              void* d_out, int out_size, void* d_ws, size_t ws_size,
                              hipStream_t stream) {
    const float* x      = (const float*)d_in[0];
    const float* logits = (const float*)d_in[1];
    const float* w1     = (const float*)d_in[2];
    const float* w3     = (const float*)d_in[3];
    const float* w2     = (const float*)d_in[4];
    float* out = (float*)d_out;

    char* ws = (char*)d_ws;
    int* off   = (int*)ws;                         // 16 ints
    int* tok   = (int*)(ws + 64);                  // 512 ints
    float* scl = (float*)(ws + 64 + 2048);         // 512 floats
    unsigned short* xs   = (unsigned short*)(ws + 8192);                         // 2 MiB
    unsigned short* hbuf = (unsigned short*)(ws + 8192 + (size_t)T_TOK * HDIM * 2);  // 4 MiB

    k_route<<<1, T_TOK, 0, stream>>>(logits, off, tok, scl);
    k_gather<<<T_TOK, 256, 0, stream>>>(x, tok, scl, xs);
    k_moe1<<<NEXP * (IDIM / G1_BN), 256, 0, stream>>>(xs, w1, w3, off, hbuf);
    k_moe2<<<NEXP * (HDIM / G2_BN), 256, 0, stream>>>(hbuf, w2, off, tok, out);
}

// Round 3
// 216.226 us; speedup vs baseline: 1.1150x; 1.1150x over previous
//
#include <hip/hip_runtime.h>

#define T_TOK 512
#define HDIM 2048
#define NEXP 8
#define IDIM 4096

#define BM 128
#define BK 64
#define G1_BN 32
#define G2_BN 16

typedef float f32x4 __attribute__((ext_vector_type(4)));
typedef __bf16 bf16x8 __attribute__((ext_vector_type(8)));
typedef unsigned short ushort8 __attribute__((ext_vector_type(8)));

// fp32 -> bf16 round-to-nearest-even
static __device__ __forceinline__ unsigned short f2bf(float f) {
    unsigned int u = __float_as_uint(f);
    u = (u + 0x7fffu + ((u >> 16) & 1u)) >> 16;
    return (unsigned short)u;
}

// async global->LDS, 16 B/lane; LDS dest = wave-uniform base + lane*16
static __device__ __forceinline__ void gload_lds16(const void* g, void* l) {
    auto gp = reinterpret_cast<const unsigned int __attribute__((address_space(1)))*>(
        reinterpret_cast<unsigned long long>(g));
    auto lp = reinterpret_cast<unsigned int __attribute__((address_space(3)))*>(
        static_cast<unsigned int>(reinterpret_cast<unsigned long long>(l)));
    __builtin_amdgcn_global_load_lds(gp, lp, 16, 0, 0);
}

// ---------------- routing ------------------------------------------------------
__global__ void k_route(const float* __restrict__ logits,
                        int* __restrict__ off, int* __restrict__ tok,
                        float* __restrict__ scale) {
    __shared__ int cnt[NEXP], cur[NEXP];
    const int t = threadIdx.x;
    if (t < NEXP) cnt[t] = 0;
    __syncthreads();
    float m = logits[t * NEXP];
    int a = 0;
#pragma unroll
    for (int j = 1; j < NEXP; ++j) {
        float v = logits[t * NEXP + j];
        if (v > m) { m = v; a = j; }
    }
    scale[t] = 1.f / (1.f + __expf(-m));
    atomicAdd(&cnt[a], 1);
    __syncthreads();
    if (t == 0) {
        int o = 0;
        for (int e = 0; e < NEXP; ++e) { off[e] = o; cur[e] = o; o += cnt[e]; }
        off[NEXP] = o;
    }
    __syncthreads();
    int r = atomicAdd(&cur[a], 1);
    tok[r] = t;
}

// ---------------- gather + scale + bf16 ---------------------------------------
__global__ void k_gather(const float* __restrict__ x, const int* __restrict__ tok,
                         const float* __restrict__ scale,
                         unsigned short* __restrict__ xs) {
    const int pos = blockIdx.x;
    const int t = tok[pos];
    const float s = scale[t];
    const int c = threadIdx.x * 8;
    const float4* src = (const float4*)(x + (size_t)t * HDIM + c);
    float4 v0 = src[0], v1 = src[1];
    ushort8 o;
    o[0] = f2bf(v0.x * s); o[1] = f2bf(v0.y * s);
    o[2] = f2bf(v0.z * s); o[3] = f2bf(v0.w * s);
    o[4] = f2bf(v1.x * s); o[5] = f2bf(v1.y * s);
    o[6] = f2bf(v1.z * s); o[7] = f2bf(v1.w * s);
    *(ushort8*)(xs + (size_t)pos * HDIM + c) = o;
}

// ---------------- GEMM1: gate/up + SiLU ----------------------------------------
// grid 8*128 blocks, 256 thr (4 waves, each M=32, N=32), C-tile 128x32 (x2 mats)
__global__ void __launch_bounds__(256, 4)
k_moe1(const unsigned short* __restrict__ xs,
       const float* __restrict__ w1,
       const float* __restrict__ w3,
       const int* __restrict__ off,
       unsigned short* __restrict__ hbuf) {
    __shared__ unsigned short sA[BM * BK];   // 16 KiB, rows 128 B, swz (row&7)<<4
    __shared__ float sB1[G1_BN * BK];        // 8 KiB, rows 256 B, swz (row&7)<<5
    __shared__ float sB3[G1_BN * BK];        // 8 KiB

    const int tid = threadIdx.x;
    const int w = tid >> 6, l = tid & 63;
    const int e = blockIdx.x >> 7;
    const int n0 = (blockIdx.x & 127) * G1_BN;
    const int pos_beg = off[e], pos_end = off[e + 1];

    const char* bw1 = (const char*)(w1 + (size_t)e * IDIM * HDIM + (size_t)n0 * HDIM);
    const char* bw3 = (const char*)(w3 + (size_t)e * IDIM * HDIM + (size_t)n0 * HDIM);

    // staging constants (lane's physical byte = base_o + l*16)
    const int a_row = w * 8 + (l >> 3);                       // + j*32
    const int a_cb  = ((l & 7) ^ (l >> 3)) << 4;              // swizzled col byte
    const int b_row = w * 4 + (l >> 4);                       // + j*16
    const int b_cb  = ((l & 15) << 4) ^ (((w * 4 + (l >> 4)) & 7) << 5);

    for (int m0 = pos_beg; m0 < pos_end; m0 += BM) {
        f32x4 zero = {0.f, 0.f, 0.f, 0.f};
        f32x4 accG[2][2], accU[2][2];
#pragma unroll
        for (int i = 0; i < 2; ++i)
#pragma unroll
            for (int j = 0; j < 2; ++j) { accG[i][j] = zero; accU[i][j] = zero; }

#pragma unroll 1
        for (int ks = 0; ks < HDIM / BK; ++ks) {
            const int k0 = ks * BK;
            // A tile 128x64 bf16, pre-swizzled source
#pragma unroll
            for (int j = 0; j < 4; ++j) {
                const int o = j * 4096 + w * 1024;
                int gr = m0 + j * 32 + a_row; gr = gr < T_TOK ? gr : T_TOK - 1;
                gload_lds16((const char*)xs + (size_t)gr * (HDIM * 2) + k0 * 2 + a_cb,
                            (char*)sA + o);
            }
            // B tiles 32x64 fp32
#pragma unroll
            for (int j = 0; j < 2; ++j) {
                const int o = j * 4096 + w * 1024;
                const size_t roff = (size_t)(j * 16 + b_row) * (HDIM * 4) + k0 * 4 + b_cb;
                gload_lds16(bw1 + roff, (char*)sB1 + o);
                gload_lds16(bw3 + roff, (char*)sB3 + o);
            }
            asm volatile("s_waitcnt vmcnt(0)" ::: "memory");
            __syncthreads();

#pragma unroll
            for (int kk = 0; kk < 2; ++kk) {
                bf16x8 a[2];
#pragma unroll
                for (int fm = 0; fm < 2; ++fm) {
                    const int row = w * 32 + fm * 16 + (l & 15);
                    const int kb = (kk * 64 + ((l >> 4) << 4)) ^ ((l & 7) << 4);
                    a[fm] = *(const bf16x8*)((const char*)sA + row * 128 + kb);
                }
#pragma unroll
                for (int fn = 0; fn < 2; ++fn) {
                    const int row = fn * 16 + (l & 15);
                    const int kb = (kk * 128 + ((l >> 4) << 5)) ^ ((l & 7) << 5);
                    const char* p1 = (const char*)sB1 + row * 256 + kb;
                    const char* p3 = (const char*)sB3 + row * 256 + kb;
                    f32x4 g0 = *(const f32x4*)p1, g1 = *(const f32x4*)(p1 + 16);
                    f32x4 u0 = *(const f32x4*)p3, u1 = *(const f32x4*)(p3 + 16);
                    bf16x8 bg, bu;
#pragma unroll
                    for (int q = 0; q < 4; ++q) {
                        bg[q] = (__bf16)g0[q]; bg[q + 4] = (__bf16)g1[q];
                        bu[q] = (__bf16)u0[q]; bu[q + 4] = (__bf16)u1[q];
                    }
#pragma unroll
                    for (int fm = 0; fm < 2; ++fm) {
                        accG[fm][fn] = __builtin_amdgcn_mfma_f32_16x16x32_bf16(
                            a[fm], bg, accG[fm][fn], 0, 0, 0);
                        accU[fm][fn] = __builtin_amdgcn_mfma_f32_16x16x32_bf16(
                            a[fm], bu, accU[fm][fn], 0, 0, 0);
                    }
                }
            }
            __syncthreads();
        }

        // epilogue: h = silu(gate) * up -> bf16
#pragma unroll
        for (int fm = 0; fm < 2; ++fm)
#pragma unroll
            for (int fn = 0; fn < 2; ++fn)
#pragma unroll
                for (int r = 0; r < 4; ++r) {
                    const int pos = m0 + w * 32 + fm * 16 + ((l >> 4) << 2) + r;
                    if (pos < pos_end) {
                        const float gv = accG[fm][fn][r];
                        const float uv = accU[fm][fn][r];
                        const float hv = gv / (1.f + __expf(-gv)) * uv;
                        hbuf[(size_t)pos * IDIM + n0 + fn * 16 + (l & 15)] = f2bf(hv);
                    }
                }
    }
}

// ---------------- GEMM2: down proj + scatter -----------------------------------
// grid 8*128 blocks, 4 waves (each M=32, N=16), C-tile 128x16, K=4096
__global__ void __launch_bounds__(256, 4)
k_moe2(const unsigned short* __restrict__ hbuf,
       const float* __restrict__ w2,
       const int* __restrict__ off,
       const int* __restrict__ tok,
       float* __restrict__ out) {
    __shared__ unsigned short sA[BM * BK];   // 16 KiB
    __shared__ float sB[G2_BN * BK];         // 4 KiB

    const int tid = threadIdx.x;
    const int w = tid >> 6, l = tid & 63;
    const int e = blockIdx.x >> 7;
    const int n0 = (blockIdx.x & 127) * G2_BN;
    const int pos_beg = off[e], pos_end = off[e + 1];
    const char* bw2 = (const char*)(w2 + (size_t)e * HDIM * IDIM + (size_t)n0 * IDIM);

    const int a_row = w * 8 + (l >> 3);
    const int a_cb  = ((l & 7) ^ (l >> 3)) << 4;
    const int b_row = w * 4 + (l >> 4);
    const int b_cb  = ((l & 15) << 4) ^ (((w * 4 + (l >> 4)) & 7) << 5);

    for (int m0 = pos_beg; m0 < pos_end; m0 += BM) {
        f32x4 zero = {0.f, 0.f, 0.f, 0.f};
        f32x4 acc[2];
        acc[0] = zero; acc[1] = zero;

#pragma unroll 1
        for (int ks = 0; ks < IDIM / BK; ++ks) {
            const int k0 = ks * BK;
#pragma unroll
            for (int j = 0; j < 4; ++j) {
                const int o = j * 4096 + w * 1024;
                int gr = m0 + j * 32 + a_row; gr = gr < T_TOK ? gr : T_TOK - 1;
                gload_lds16((const char*)hbuf + (size_t)gr * (IDIM * 2) + k0 * 2 + a_cb,
                            (char*)sA + o);
            }
            {
                const int o = w * 1024;
                gload_lds16(bw2 + (size_t)b_row * (IDIM * 4) + k0 * 4 + b_cb,
                            (char*)sB + o);
            }
            asm volatile("s_waitcnt vmcnt(0)" ::: "memory");
            __syncthreads();

#pragma unroll
            for (int kk = 0; kk < 2; ++kk) {
                const int brow = l & 15;
                const int bkb = (kk * 128 + ((l >> 4) << 5)) ^ ((l & 7) << 5);
                const char* pb = (const char*)sB + brow * 256 + bkb;
                f32x4 b0 = *(const f32x4*)pb, b1 = *(const f32x4*)(pb + 16);
                bf16x8 bb;
#pragma unroll
                for (int q = 0; q < 4; ++q) {
                    bb[q] = (__bf16)b0[q]; bb[q + 4] = (__bf16)b1[q];
                }
#pragma unroll
                for (int fm = 0; fm < 2; ++fm) {
                    const int row = w * 32 + fm * 16 + (l & 15);
                    const int kb = (kk * 64 + ((l >> 4) << 4)) ^ ((l & 7) << 4);
                    bf16x8 a = *(const bf16x8*)((const char*)sA + row * 128 + kb);
                    acc[fm] = __builtin_amdgcn_mfma_f32_16x16x32_bf16(a, bb, acc[fm], 0, 0, 0);
                }
            }
            __syncthreads();
        }

#pragma unroll
        for (int fm = 0; fm < 2; ++fm)
#pragma unroll
            for (int r = 0; r < 4; ++r) {
                const int pos = m0 + w * 32 + fm * 16 + ((l >> 4) << 2) + r;
                if (pos < pos_end) {
                    const int t = tok[pos];
                    out[(size_t)t * HDIM + n0 + (l & 15)] = acc[fm][r];
                }
            }
    }
}

extern "C" void kernel_launch(void* const* d_in, const int* in_sizes, int n_in,
                              void* d_out, int out_size, void* d_ws, size_t ws_size,
                              hipStream_t stream) {
    const float* x      = (const float*)d_in[0];
    const float* logits = (const float*)d_in[1];
    const float* w1     = (const float*)d_in[2];
    const float* w3     = (const float*)d_in[3];
    const float* w2     = (const float*)d_in[4];
    float* out = (float*)d_out;

    char* ws = (char*)d_ws;
    int* off   = (int*)ws;                          // 9 ints
    int* tok   = (int*)(ws + 64);                   // 512 ints
    float* scl = (float*)(ws + 64 + 2048);          // 512 floats
    unsigned short* xs   = (unsigned short*)(ws + 8192);                             // 2 MiB
    unsigned short* hbuf = (unsigned short*)(ws + 8192 + (size_t)T_TOK * HDIM * 2);  // 4 MiB

    k_route<<<1, T_TOK, 0, stream>>>(logits, off, tok, scl);
    k_gather<<<T_TOK, 256, 0, stream>>>(x, tok, scl, xs);
    k_moe1<<<NEXP * (IDIM / G1_BN), 256, 0, stream>>>(xs, w1, w3, off, hbuf);
    k_moe2<<<NEXP * (HDIM / G2_BN), 256, 0, stream>>>(hbuf, w2, off, tok, out);
}